// Round 6
// baseline (361.873 us; speedup 1.0000x reference)
//
#include <hip/hip_runtime.h>

// ---------------- problem constants ----------------
// x:[N,128] W1:[128,128] b1:[128] W2:[128,64] b2:[64] edge_index:[2,E]
// out:[N,64] fp32. Intermediates bf16 in CHANNEL-GROUP-MAJOR layout
// [C/16][N][16] so each XCD (blockIdx%8) gathers only its L2-resident slice.

static constexpr int BSHIFT = 7;          // 128 node ids per coarse bucket
static constexpr int BWIDTH = 1 << BSHIFT;
static constexpr int MAXBUCK = 2048;      // supports N <= 262144 (pack needs N < 2^20)
static constexpr int NPART = 256;         // partition/hist grid size

// ---------------- workspace layout (bytes) ----------------
static constexpr size_t OFF_ROW  = 0;         // u32[N+1]
static constexpr size_t OFF_CCNT = 524288;    // u32[MAXBUCK+1]
static constexpr size_t OFF_COFF = 540672;    // u32[MAXBUCK+1]
static constexpr size_t OFF_DINV = 557056;    // f32[N]
static constexpr size_t OFF_CSR  = 1048576;   // i32[E]            (6.4 MB)
static constexpr size_t OFF_HS1  = 8388608;   // bf16[8][N][16] 25.6 MB; aliases part u32[E]
static constexpr size_t OFF_OUT1 = 35651584;  // bf16[8][N][16] 25.6 MB
static constexpr size_t OFF_HS2  = 62914560;  // bf16[4][N][16] 12.8 MB
static constexpr size_t OFF_H2   = 75714560;  // u32[MAXBUCK*NPART] (2 MB)

// ---------------- bf16 helpers ----------------
__device__ __forceinline__ unsigned short f2bf(float f) {  // RNE
    unsigned u = __float_as_uint(f);
    u += 0x7fffu + ((u >> 16) & 1u);
    return (unsigned short)(u >> 16);
}

typedef __attribute__((ext_vector_type(8))) short bf16x8;
typedef __attribute__((ext_vector_type(4))) float f32x4;

// accumulate 8 bf16 (packed in uint4) into 8 fp32
__device__ __forceinline__ void acc8(const uint4 u, float* s) {
    s[0] += __uint_as_float(u.x << 16); s[1] += __uint_as_float(u.x & 0xffff0000u);
    s[2] += __uint_as_float(u.y << 16); s[3] += __uint_as_float(u.y & 0xffff0000u);
    s[4] += __uint_as_float(u.z << 16); s[5] += __uint_as_float(u.z & 0xffff0000u);
    s[6] += __uint_as_float(u.w << 16); s[7] += __uint_as_float(u.w & 0xffff0000u);
}

// ---------------- edge accessors (flag: 1 = int32 layout) ----------------
__device__ __forceinline__ int edge_dst(const unsigned* w, unsigned flag,
                                        int e, int E) {
    return flag ? (int)w[E + e] : (int)w[2 * E + 2 * e];
}
__device__ __forceinline__ int edge_src(const unsigned* w, unsigned flag,
                                        int e, int E) {
    return flag ? (int)w[e] : (int)w[2 * e];
}
// block-local dtype detect: int64 => high words all zero in our sample.
// (valid for both layouts: index 2i+1 < 2E words, the minimum buffer size)
__device__ __forceinline__ unsigned detect_local(const unsigned* w, int e0,
                                                 int e1) {
    int si = e0 + (int)threadIdx.x;
    int pred = (si < e1) ? (w[2 * si + 1] != 0u) : 0;
    return (unsigned)(__syncthreads_or(pred) != 0);
}

// ---------------- pass A: coarse histogram (stores per-block hist) ---------
__global__ __launch_bounds__(1024) void coarse_hist_kernel(
    const unsigned* __restrict__ w, unsigned* __restrict__ ccnt,
    unsigned* __restrict__ h2, int E, int nbuck) {
    __shared__ unsigned hist[MAXBUCK];
    for (int i = threadIdx.x; i < nbuck; i += 1024) hist[i] = 0;
    const int per = (E + gridDim.x - 1) / gridDim.x;
    const int e0 = blockIdx.x * per, e1 = min(E, e0 + per);
    const unsigned f = detect_local(w, e0, e1);   // includes barrier
    for (int e = e0 + (int)threadIdx.x; e < e1; e += 1024)
        atomicAdd(&hist[edge_dst(w, f, e, E) >> BSHIFT], 1u);
    __syncthreads();
    for (int i = threadIdx.x; i < nbuck; i += 1024) {
        unsigned h = hist[i];
        h2[(size_t)i * NPART + blockIdx.x] = h;
        if (h) atomicAdd(&ccnt[i], h);
    }
}

// ---------------- coarse scan: coff = exclusive_scan(ccnt) ----------------
__global__ __launch_bounds__(1024) void coarse_scan_kernel(
    const unsigned* __restrict__ ccnt, unsigned* __restrict__ coff, int nbuck) {
    __shared__ unsigned sh[1024];
    const int t = threadIdx.x;
    unsigned run = 0;
    for (int b0 = 0; b0 < nbuck; b0 += 1024) {
        unsigned v = (b0 + t < nbuck) ? ccnt[b0 + t] : 0u;
        sh[t] = v;
        __syncthreads();
        for (int off = 1; off < 1024; off <<= 1) {
            unsigned a = (t >= off) ? sh[t - off] : 0u;
            __syncthreads();
            sh[t] += a;
            __syncthreads();
        }
        if (b0 + t < nbuck) coff[b0 + t] = run + sh[t] - v;
        run += sh[1023];
        __syncthreads();
    }
    if (t == 0) coff[nbuck] = run;   // == E
}

// ---------------- off2d: h2[b][blk] -> per-block write cursor --------------
__global__ __launch_bounds__(NPART) void off2d_kernel(
    unsigned* __restrict__ h2, const unsigned* __restrict__ coff) {
    __shared__ unsigned sh[NPART];
    const int b = blockIdx.x, t = threadIdx.x;
    unsigned v = h2[(size_t)b * NPART + t];
    sh[t] = v;
    __syncthreads();
#pragma unroll
    for (int off = 1; off < NPART; off <<= 1) {
        unsigned a = (t >= off) ? sh[t - off] : 0u;
        __syncthreads();
        sh[t] += a;
        __syncthreads();
    }
    h2[(size_t)b * NPART + t] = coff[b] + sh[t] - v;   // exclusive + base
}

// ---------------- pass B: partition (packed 4 B entries) ----------------
// part entry = src | (dst&127)<<20  (valid: N < 2^20)
__global__ __launch_bounds__(1024) void partition_kernel(
    const unsigned* __restrict__ w, const unsigned* __restrict__ h2,
    unsigned* __restrict__ part, int E, int nbuck) {
    __shared__ unsigned lcur[MAXBUCK];
    for (int i = threadIdx.x; i < nbuck; i += 1024)
        lcur[i] = h2[(size_t)i * NPART + blockIdx.x];
    const int per = (E + gridDim.x - 1) / gridDim.x;
    const int e0 = blockIdx.x * per, e1 = min(E, e0 + per);
    const unsigned f = detect_local(w, e0, e1);   // includes barrier
    for (int e = e0 + (int)threadIdx.x; e < e1; e += 1024) {
        int d = edge_dst(w, f, e, E);
        int s = edge_src(w, f, e, E);
        unsigned pos = atomicAdd(&lcur[d >> BSHIFT], 1u);
        part[pos] = (unsigned)s | ((unsigned)(d & (BWIDTH - 1)) << 20);
    }
}

// ---------------- pass C: per-bucket deg + scan -> row/dinv + CSR ----------
// coff[b] == row[b<<BSHIFT] by construction, so the bucket-local exclusive
// scan IS the global row array — no separate deg/scan kernels needed.
__global__ __launch_bounds__(256) void bucket_csr_kernel(
    const unsigned* __restrict__ part, const unsigned* __restrict__ coff,
    unsigned* __restrict__ row, float* __restrict__ dinv,
    int* __restrict__ csr, int N, int nbuck) {
    __shared__ unsigned cnt[BWIDTH];
    __shared__ unsigned sc[BWIDTH];
    __shared__ unsigned cur[BWIDTH];
    const int b = blockIdx.x, base = b << BSHIFT, t = threadIdx.x;
    if (t < BWIDTH) cnt[t] = 0;
    __syncthreads();
    const int e0 = (int)coff[b], e1 = (int)coff[b + 1];
    for (int e = e0 + t; e < e1; e += 256)
        atomicAdd(&cnt[part[e] >> 20], 1u);
    __syncthreads();
    if (t < BWIDTH) sc[t] = cnt[t];
    __syncthreads();
#pragma unroll
    for (int off = 1; off < BWIDTH; off <<= 1) {
        unsigned a = (t < BWIDTH && t >= off) ? sc[t - off] : 0u;
        __syncthreads();
        if (t < BWIDTH) sc[t] += a;
        __syncthreads();
    }
    if (t < BWIDTH) {
        unsigned ex = (unsigned)e0 + sc[t] - cnt[t];
        cur[t] = ex;
        if (base + t < N) {
            row[base + t] = ex;
            dinv[base + t] = rsqrtf((float)cnt[t] + 1.0f);
        }
    }
    if (b == 0 && t == 0) row[N] = coff[nbuck];   // == E
    __syncthreads();
    for (int e = e0 + t; e < e1; e += 256) {
        unsigned pk = part[e];
        unsigned p = atomicAdd(&cur[pk >> 20], 1u);
        csr[p] = (int)(pk & 0xFFFFFu);
    }
}

// ---------------- MFMA GEMM: outg = group-major bf16 of (A @ B) * dinv -----
// 128xBN tile, K=128, 16x16x32 bf16 MFMA. A-fragments load DIRECT from
// global (contiguous per lane, full line coverage); only B staged in LDS
// (swizzled to fragment order). out layout: [BN/16][M][16].
template <int BN, bool ABF16>
__global__ __launch_bounds__(256) void gemm_mfma(
    const void* __restrict__ Av, const float* __restrict__ B,
    const float* __restrict__ dinv, unsigned short* __restrict__ outg, int M) {
    constexpr int NT = BN / 16;          // col tiles (8 or 4)
    __shared__ short sB[NT * 2048];      // NT * 4ks * 512 bf16 (32/16 KB)

    const int t = threadIdx.x;
    const int row0 = blockIdx.x * 128;
    const int w = t >> 6, lane = t & 63;
    const int m = lane & 15, q = lane >> 4;

    // ---- stage B (fp32 [128][BN] -> swizzled bf16) ----
    for (int g = t; g < BN * 32; g += 256) {
        int n = g % BN, k0 = (g / BN) * 4;
        float f0 = B[(size_t)(k0 + 0) * BN + n];
        float f1 = B[(size_t)(k0 + 1) * BN + n];
        float f2 = B[(size_t)(k0 + 2) * BN + n];
        float f3 = B[(size_t)(k0 + 3) * BN + n];
        ushort4 u;
        u.x = f2bf(f0); u.y = f2bf(f1); u.z = f2bf(f2); u.w = f2bf(f3);
        int off = ((((n >> 4) * 4 + (k0 >> 5)) * 16 + (n & 15)) * 4 +
                   ((k0 >> 3) & 3)) * 8 + (k0 & 4);
        *(ushort4*)(sB + off) = u;
    }

    // ---- A fragments direct from global ----
    bf16x8 a[2][4];
#pragma unroll
    for (int lt = 0; lt < 2; lt++) {
        const int row = row0 + (w * 2 + lt) * 16 + m;
        const bool ok = row < M;
#pragma unroll
        for (int ks = 0; ks < 4; ks++) {
            const int k = ks * 32 + q * 8;
            if (ABF16) {
                uint4 v = make_uint4(0u, 0u, 0u, 0u);
                if (ok)
                    v = *(const uint4*)((const unsigned short*)Av +
                                        ((size_t)(k >> 4) * M + row) * 16 + (k & 15));
                a[lt][ks] = *(const bf16x8*)&v;
            } else {
                float4 v0 = make_float4(0.f, 0.f, 0.f, 0.f), v1 = v0;
                if (ok) {
                    const float* A = (const float*)Av + (size_t)row * 128 + k;
                    v0 = *(const float4*)A;
                    v1 = *(const float4*)(A + 4);
                }
                bf16x8 av;
                av[0] = (short)f2bf(v0.x); av[1] = (short)f2bf(v0.y);
                av[2] = (short)f2bf(v0.z); av[3] = (short)f2bf(v0.w);
                av[4] = (short)f2bf(v1.x); av[5] = (short)f2bf(v1.y);
                av[6] = (short)f2bf(v1.z); av[7] = (short)f2bf(v1.w);
                a[lt][ks] = av;
            }
        }
    }
    __syncthreads();

    f32x4 acc[2][NT];
#pragma unroll
    for (int lt = 0; lt < 2; lt++)
#pragma unroll
        for (int nt = 0; nt < NT; nt++) acc[lt][nt] = (f32x4){0.f, 0.f, 0.f, 0.f};

    const int fb = (m * 4 + q) * 8;
#pragma unroll
    for (int ks = 0; ks < 4; ks++) {
#pragma unroll
        for (int nt = 0; nt < NT; nt++) {
            bf16x8 b = *(const bf16x8*)(sB + (nt * 4 + ks) * 512 + fb);
            acc[0][nt] = __builtin_amdgcn_mfma_f32_16x16x32_bf16(a[0][ks], b, acc[0][nt], 0, 0, 0);
            acc[1][nt] = __builtin_amdgcn_mfma_f32_16x16x32_bf16(a[1][ks], b, acc[1][nt], 0, 0, 0);
        }
    }

    // ---- epilogue: scale by dinv, store bf16 group-major ----
#pragma unroll
    for (int lt = 0; lt < 2; lt++) {
#pragma unroll
        for (int r = 0; r < 4; r++) {
            int row = row0 + w * 32 + lt * 16 + q * 4 + r;
            if (row < M) {
                float s = dinv[row];
#pragma unroll
                for (int nt = 0; nt < NT; nt++)
                    outg[((size_t)nt * M + row) * 16 + m] = f2bf(acc[lt][nt][r] * s);
            }
        }
    }
}

// ---------------- XCD-sliced gather aggregation + fused epilogue ----------
// hsg: group-major [C/16][N][16] bf16. Each block handles ONE 16-channel
// group for 128 nodes; blockIdx%8 (XCD round-robin) selects the group so a
// given XCD only ever touches a 16-ch slice (3.2/1.6 MB -> L2-resident).
// 2 lanes per node (uint4 = 8 ch each).
template <int C, bool RELU, bool OUTBF>
__global__ __launch_bounds__(256) void agg_sliced(
    const int* __restrict__ csr, const unsigned* __restrict__ row,
    const unsigned short* __restrict__ hsg, const float* __restrict__ dinv,
    const float* __restrict__ bias, void* __restrict__ outv, int N) {
    int cg, chunk;
    const int bi = blockIdx.x;
    if (C == 128) { cg = bi & 7; chunk = bi >> 3; }
    else { const int g = bi & 7; cg = g >> 1; chunk = (bi >> 3) * 2 + (g & 1); }
    const int slot = threadIdx.x >> 1, l = threadIdx.x & 1;
    const int i = chunk * 128 + slot;
    if (i >= N) return;

    const unsigned short* tab = hsg + (size_t)cg * N * 16;
    const int co = l * 8;

    float s[8] = {0.f, 0.f, 0.f, 0.f, 0.f, 0.f, 0.f, 0.f};
    acc8(*(const uint4*)(tab + (size_t)i * 16 + co), s);   // self-loop term

    const int rs = (int)row[i], re = (int)row[i + 1];
    for (int e0 = rs; e0 < re; e0 += 2) {
        int idx = (e0 + l < re) ? csr[e0 + l] : 0;
        int sa = __shfl(idx, 0, 2);
        int sb = __shfl(idx, 1, 2);
        const bool two = (e0 + 1 < re);
        uint4 v0 = *(const uint4*)(tab + (size_t)sa * 16 + co);
        uint4 v1 = *(const uint4*)(tab + (size_t)(two ? sb : sa) * 16 + co);
        acc8(v0, s);
        if (two) acc8(v1, s);
    }

    const float sc = dinv[i];
    const int cb = cg * 16 + co;
    const float4 ba = *(const float4*)(bias + cb);
    const float4 bb = *(const float4*)(bias + cb + 4);
    float o0 = s[0] * sc + ba.x, o1 = s[1] * sc + ba.y;
    float o2 = s[2] * sc + ba.z, o3 = s[3] * sc + ba.w;
    float o4 = s[4] * sc + bb.x, o5 = s[5] * sc + bb.y;
    float o6 = s[6] * sc + bb.z, o7 = s[7] * sc + bb.w;
    if (RELU) {
        o0 = fmaxf(o0, 0.f); o1 = fmaxf(o1, 0.f); o2 = fmaxf(o2, 0.f);
        o3 = fmaxf(o3, 0.f); o4 = fmaxf(o4, 0.f); o5 = fmaxf(o5, 0.f);
        o6 = fmaxf(o6, 0.f); o7 = fmaxf(o7, 0.f);
    }
    if (OUTBF) {
        // group-major bf16 out (same layout family as hsg)
        uint4 u;
        u.x = (unsigned)f2bf(o0) | ((unsigned)f2bf(o1) << 16);
        u.y = (unsigned)f2bf(o2) | ((unsigned)f2bf(o3) << 16);
        u.z = (unsigned)f2bf(o4) | ((unsigned)f2bf(o5) << 16);
        u.w = (unsigned)f2bf(o6) | ((unsigned)f2bf(o7) << 16);
        *(uint4*)((unsigned short*)outv + ((size_t)cg * N + i) * 16 + co) = u;
    } else {
        // fp32 row-major final output [N][C]
        float* o = (float*)outv + (size_t)i * C + cb;
        *(float4*)o = make_float4(o0, o1, o2, o3);
        *(float4*)(o + 4) = make_float4(o4, o5, o6, o7);
    }
}

// ---------------- launch ----------------
extern "C" void kernel_launch(void* const* d_in, const int* in_sizes, int n_in,
                              void* d_out, int out_size, void* d_ws,
                              size_t ws_size, hipStream_t stream) {
    const float* x  = (const float*)d_in[0];
    const float* W1 = (const float*)d_in[1];
    const float* b1 = (const float*)d_in[2];
    const float* W2 = (const float*)d_in[3];
    const float* b2 = (const float*)d_in[4];
    const unsigned* ew = (const unsigned*)d_in[5];
    const int E = in_sizes[5] / 2;        // 1,600,000
    const int N = in_sizes[0] / 128;      // 100,000
    const int nbuck = (N + BWIDTH - 1) >> BSHIFT;   // 782
    const int chunks = (N + 127) / 128;             // 782

    char* ws = (char*)d_ws;
    unsigned* row  = (unsigned*)(ws + OFF_ROW);
    unsigned* ccnt = (unsigned*)(ws + OFF_CCNT);
    unsigned* coff = (unsigned*)(ws + OFF_COFF);
    float* dinv    = (float*)(ws + OFF_DINV);
    int* csr       = (int*)(ws + OFF_CSR);
    unsigned short* hs1g  = (unsigned short*)(ws + OFF_HS1);
    unsigned short* out1g = (unsigned short*)(ws + OFF_OUT1);
    unsigned short* hs2g  = (unsigned short*)(ws + OFF_HS2);
    unsigned* h2   = (unsigned*)(ws + OFF_H2);
    unsigned* part = (unsigned*)(ws + OFF_HS1);  // dead before gemm1 writes hs1g

    hipMemsetAsync(ccnt, 0, (size_t)(nbuck + 1) * 4, stream);

    // ---- CSR build (6 dispatches incl. memset; row/dinv fused in) ----
    coarse_hist_kernel<<<NPART, 1024, 0, stream>>>(ew, ccnt, h2, E, nbuck);
    coarse_scan_kernel<<<1, 1024, 0, stream>>>(ccnt, coff, nbuck);
    off2d_kernel<<<nbuck, NPART, 0, stream>>>(h2, coff);
    partition_kernel<<<NPART, 1024, 0, stream>>>(ew, h2, part, E, nbuck);
    bucket_csr_kernel<<<nbuck, 256, 0, stream>>>(part, coff, row, dinv, csr,
                                                 N, nbuck);

    // ---- layer 1 (C=128) ----
    gemm_mfma<128, false><<<chunks, 256, 0, stream>>>(x, W1, dinv, hs1g, N);
    agg_sliced<128, true, true><<<chunks * 8, 256, 0, stream>>>(
        csr, row, hs1g, dinv, b1, out1g, N);

    // ---- layer 2 (C=64) ----
    gemm_mfma<64, true><<<chunks, 256, 0, stream>>>(out1g, W2, dinv, hs2g, N);
    agg_sliced<64, false, false><<<((chunks + 1) / 2) * 8, 256, 0, stream>>>(
        csr, row, hs2g, dinv, b2, d_out, N);
}